// Round 1
// baseline (14524.747 us; speedup 1.0000x reference)
//
#include <hip/hip_runtime.h>

#define T_STEPS 512
#define BATCH 64
#define FDIM 256
#define HDIM 1024
#define CDIM 257

typedef __attribute__((ext_vector_type(8))) short short8;
typedef __attribute__((ext_vector_type(4))) short short4_t;
typedef __attribute__((ext_vector_type(4))) float float4_t;

__device__ __forceinline__ short f2bf(float f) {
  unsigned u = __builtin_bit_cast(unsigned, f);
  unsigned r = (u + 0x7fffu + ((u >> 16) & 1u)) >> 16;   // RNE
  return (short)(r & 0xffffu);
}

__device__ __forceinline__ float sigmoid_f(float x) {
  return 1.0f / (1.0f + __expf(-x));
}
__device__ __forceinline__ float tanh_f(float x) {
  float s = __expf(-2.0f * fabsf(x));
  float t = (1.0f - s) / (1.0f + s);
  return (x < 0.0f) ? -t : t;
}

// ---------------------------------------------------------------------------
// prep: fco fp32 -> bf16 (padded to 272 rows), zero h double-buffer + counters
// grid: 272 x 256  (tid 0..69631, 4 fco elems each = 278528 exactly)
// ---------------------------------------------------------------------------
__global__ void prep_kernel(const float* __restrict__ fco_w,
                            short* __restrict__ fcob,
                            short* __restrict__ hbuf,
                            unsigned* __restrict__ cnt)
{
  const int tid = blockIdx.x * 256 + threadIdx.x;
  {
    const int idx = tid * 4;
    const int c = idx >> 10, k = idx & 1023;
    short4_t o;
    if (c < CDIM) {
      const float4_t f = *(const float4_t*)(fco_w + c * HDIM + k);
      o[0] = f2bf(f[0]); o[1] = f2bf(f[1]); o[2] = f2bf(f[2]); o[3] = f2bf(f[3]);
    } else {
      o[0] = 0; o[1] = 0; o[2] = 0; o[3] = 0;
    }
    *(short4_t*)(fcob + idx) = o;
  }
  if (tid < 16384) {   // 2*64*1024 shorts / 8
    short8 z = (short8){0,0,0,0,0,0,0,0};
    *(short8*)(hbuf + tid * 8) = z;
  }
  if (tid < 512) cnt[tid] = 0;
}

// ---------------------------------------------------------------------------
// persistent LSTM kernel: 256 WGs = 64 col-groups x 4 batch-quarters,
// 256 threads (4 waves). Wave w owns K-chunk w (256 of 1024) for all 4 gates.
// Weights live in registers as MFMA A-frags. One __syncthreads per step.
// Cross-WG sync: monotone counters per (bq, kchunk), release/acquire agent.
// ---------------------------------------------------------------------------
__global__ __launch_bounds__(256, 1) void lstm_kernel(
    const float* __restrict__ x,
    const float* __restrict__ wfx, const float* __restrict__ wix,
    const float* __restrict__ wox, const float* __restrict__ wcx,
    const float* __restrict__ bfx, const float* __restrict__ bix,
    const float* __restrict__ box, const float* __restrict__ bcx,
    const float* __restrict__ wfh, const float* __restrict__ wih,
    const float* __restrict__ woh, const float* __restrict__ wch,
    short* __restrict__ hs, short* __restrict__ hbuf,
    unsigned* __restrict__ cnt)
{
  const int tid  = threadIdx.x;
  const int lane = tid & 63;
  const int w    = tid >> 6;      // wave id == K-chunk id
  const int quad = lane >> 4;
  const int lm   = lane & 15;
  const int cg   = blockIdx.x & 63;   // column group (16 h-cols)
  const int bq   = blockIdx.x >> 6;   // batch quarter (16 rows)

  // zbuf[parity][slot = w*4+g][b(16) stride 20][i-quad 4]  (fp32, b128-aligned)
  __shared__ float zbuf[2][16 * 320];

  const float* Wh[4] = {wfh, wih, woh, wch};
  const float* Wx[4] = {wfx, wix, wox, wcx};
  const float* Bx[4] = {bfx, bix, box, bcx};

  // ---- preload weight A-fragments (bf16), K-split by wave ----
  // A[m = lane&15 -> gate-col][k = quad*8 + j]
  short8 wr[4][8];   // recurrent: gate g, local k-tile (global kt = w*8+ktl)
  short8 wxf[4][2];  // input proj: gate g, local k-tile (global kt2 = w*2+ktl)
#pragma unroll
  for (int g = 0; g < 4; ++g) {
    const float* rw = Wh[g] + (cg * 16 + lm) * HDIM;
#pragma unroll
    for (int ktl = 0; ktl < 8; ++ktl) {
      const float* pk = rw + (w * 8 + ktl) * 32 + quad * 8;
      short8 a;
#pragma unroll
      for (int j = 0; j < 8; ++j) a[j] = f2bf(pk[j]);
      wr[g][ktl] = a;
    }
    const float* rx = Wx[g] + (cg * 16 + lm) * FDIM;
#pragma unroll
    for (int ktl = 0; ktl < 2; ++ktl) {
      const float* pk = rx + (w * 2 + ktl) * 32 + quad * 8;
      short8 a;
#pragma unroll
      for (int j = 0; j < 8; ++j) a[j] = f2bf(pk[j]);
      wxf[g][ktl] = a;
    }
  }

  // wave0 epilogue state: bias per (g, i4*4+r) and cell state (4 cells/lane)
  float4_t biasv[4];
  float cst[4] = {0.f, 0.f, 0.f, 0.f};
  {
    const int i4 = lane >> 4;
#pragma unroll
    for (int g = 0; g < 4; ++g) {
#pragma unroll
      for (int r = 0; r < 4; ++r)
        biasv[g][r] = Bx[g][cg * 16 + i4 * 4 + r];
    }
  }

  unsigned* myc   = cnt + (bq * 4 + w) * 32;          // counter this wave consumes
  unsigned* prodc = cnt + (bq * 4 + (cg >> 4)) * 32;  // counter this WG produces

  for (int t = 0; t < T_STEPS; ++t) {
    const int p = t & 1;

    // prefetch x B-frags (no h dependency: overlap LIC latency with spin)
    float4_t xf[2][2];
    {
      const float* xb = x + ((t * BATCH) + bq * 16 + lm) * FDIM;
#pragma unroll
      for (int i = 0; i < 2; ++i) {
        const float* pk = xb + (w * 2 + i) * 32 + quad * 8;
        xf[i][0] = *(const float4_t*)(pk);
        xf[i][1] = *(const float4_t*)(pk + 4);
      }
    }

    // wait until all 16 producers of our K-chunk flagged h(t-1)
    if (lane == 0) {
      const unsigned want = (unsigned)(16 * t);
      while (__hip_atomic_load(myc, __ATOMIC_RELAXED, __HIP_MEMORY_SCOPE_AGENT) < want) { }
    }
    __threadfence();   // acquire: invalidate caches before reading h(t-1)

    // convert x frags to bf16
    short8 bx[2];
#pragma unroll
    for (int i = 0; i < 2; ++i) {
      short8 a;
      a[0] = f2bf(xf[i][0][0]); a[1] = f2bf(xf[i][0][1]);
      a[2] = f2bf(xf[i][0][2]); a[3] = f2bf(xf[i][0][3]);
      a[4] = f2bf(xf[i][1][0]); a[5] = f2bf(xf[i][1][1]);
      a[6] = f2bf(xf[i][1][2]); a[7] = f2bf(xf[i][1][3]);
      bx[i] = a;
    }

    // h(t-1) B-frags for our K-chunk, straight from global broadcast buffer.
    // B[k = quad*8+j][n = lm -> batch row]: 16B/lane, quads tile 64B lines.
    short8 bh[8];
    {
      const short* hb = hbuf + (p ^ 1) * (BATCH * HDIM) + (bq * 16 + lm) * HDIM;
#pragma unroll
      for (int ktl = 0; ktl < 8; ++ktl)
        bh[ktl] = *(const short8*)(hb + (w * 8 + ktl) * 32 + quad * 8);
    }

    float4_t acc[4];
#pragma unroll
    for (int g = 0; g < 4; ++g) acc[g] = (float4_t){0.f, 0.f, 0.f, 0.f};

#pragma unroll
    for (int i = 0; i < 2; ++i) {
#pragma unroll
      for (int g = 0; g < 4; ++g)
        acc[g] = __builtin_amdgcn_mfma_f32_16x16x32_bf16(wxf[g][i], bx[i], acc[g], 0, 0, 0);
    }
#pragma unroll
    for (int ktl = 0; ktl < 8; ++ktl) {
#pragma unroll
      for (int g = 0; g < 4; ++g)
        acc[g] = __builtin_amdgcn_mfma_f32_16x16x32_bf16(wr[g][ktl], bh[ktl], acc[g], 0, 0, 0);
    }

    // partial z (K-chunk) -> LDS. D rows = quad*4+r (i), cols = lm (b).
#pragma unroll
    for (int g = 0; g < 4; ++g)
      *(float4_t*)(&zbuf[p][(w * 4 + g) * 320 + lm * 20 + quad * 4]) = acc[g];

    __syncthreads();

    if (w == 0) {
      const int b = lane & 15, i4 = lane >> 4;   // cell (i = i4*4+r, b)
      const float* zb = &zbuf[p][b * 20 + i4 * 4];
      float4_t zs[4];
#pragma unroll
      for (int g = 0; g < 4; ++g) {
        float4_t v0 = *(const float4_t*)(zb + (0  + g) * 320);
        float4_t v1 = *(const float4_t*)(zb + (4  + g) * 320);
        float4_t v2 = *(const float4_t*)(zb + (8  + g) * 320);
        float4_t v3 = *(const float4_t*)(zb + (12 + g) * 320);
        zs[g] = (v0 + v1) + (v2 + v3) + biasv[g];
      }
      short4_t hv;
#pragma unroll
      for (int r = 0; r < 4; ++r) {
        float ff = sigmoid_f(zs[0][r]);
        float ii = sigmoid_f(zs[1][r]);
        float oo = sigmoid_f(zs[2][r]);
        float aa = tanh_f(zs[3][r]);
        float cn = ii * aa + ff * cst[r];
        cst[r] = cn;
        hv[r] = f2bf(oo * tanh_f(cn));
      }
      const int bg  = bq * 16 + b;
      const int col = cg * 16 + i4 * 4;
      *(short4_t*)(hbuf + p * (BATCH * HDIM) + bg * HDIM + col) = hv;
      *(short4_t*)(hs + ((t * BATCH) + bg) * HDIM + col) = hv;
      __threadfence();   // release: drain stores + writeback before flagging
      if (lane == 0)
        __hip_atomic_fetch_add(prodc, 1u, __ATOMIC_RELAXED, __HIP_MEMORY_SCOPE_AGENT);
    }
  }
}

// ---------------------------------------------------------------------------
// output projection: out[m][c] = sum_k hs[m][k]*fco[c][k] + bias[c]
// M=32768 (t*64+b), N=257 (padded 272), K=1024. A-frags in regs, B from global.
// grid: 512 x 256 (each WG: 64 rows; wave w -> m-tile w)
// ---------------------------------------------------------------------------
__global__ __launch_bounds__(256, 2) void outproj_kernel(
    const short* __restrict__ hs,
    const short* __restrict__ fcob,
    const float* __restrict__ fco_bias,
    float* __restrict__ out)
{
  const int tid = threadIdx.x, lane = tid & 63, w = tid >> 6;
  const int quad = lane >> 4, lm = lane & 15;
  const int blk = blockIdx.x;

  short8 afr[32];
  const short* ar = hs + (blk * 64 + w * 16 + lm) * HDIM;
#pragma unroll
  for (int kt = 0; kt < 32; ++kt)
    afr[kt] = *(const short8*)(ar + kt * 32 + quad * 8);

  for (int nt = 0; nt < 17; ++nt) {
    float4_t a0 = (float4_t){0.f,0.f,0.f,0.f}, a1 = (float4_t){0.f,0.f,0.f,0.f};
    const short* br = fcob + (nt * 16 + lm) * HDIM + quad * 8;
#pragma unroll
    for (int kt = 0; kt < 32; kt += 2) {
      short8 b0 = *(const short8*)(br + kt * 32);
      a0 = __builtin_amdgcn_mfma_f32_16x16x32_bf16(afr[kt], b0, a0, 0, 0, 0);
      short8 b1 = *(const short8*)(br + (kt + 1) * 32);
      a1 = __builtin_amdgcn_mfma_f32_16x16x32_bf16(afr[kt + 1], b1, a1, 0, 0, 0);
    }
    const int c = nt * 16 + lm;
    if (c < CDIM) {
      const float bias = fco_bias[c];
      const int mb = blk * 64 + w * 16 + quad * 4;
#pragma unroll
      for (int r = 0; r < 4; ++r)
        out[(mb + r) * CDIM + c] = a0[r] + a1[r] + bias;
    }
  }
}

// ---------------------------------------------------------------------------
extern "C" void kernel_launch(void* const* d_in, const int* in_sizes, int n_in,
                              void* d_out, int out_size, void* d_ws, size_t ws_size,
                              hipStream_t stream) {
  (void)in_sizes; (void)n_in; (void)out_size; (void)ws_size;
  const float* x     = (const float*)d_in[0];
  const float* wfx_w = (const float*)d_in[1];
  const float* wfx_b = (const float*)d_in[2];
  const float* wix_w = (const float*)d_in[3];
  const float* wix_b = (const float*)d_in[4];
  const float* wox_w = (const float*)d_in[5];
  const float* wox_b = (const float*)d_in[6];
  const float* wcx_w = (const float*)d_in[7];
  const float* wcx_b = (const float*)d_in[8];
  const float* wfh_w = (const float*)d_in[9];
  const float* wih_w = (const float*)d_in[10];
  const float* woh_w = (const float*)d_in[11];
  const float* wch_w = (const float*)d_in[12];
  const float* fco_w = (const float*)d_in[13];
  const float* fco_b = (const float*)d_in[14];
  float* out = (float*)d_out;

  char* ws = (char*)d_ws;
  short*    hs   = (short*)(ws);                                   // 67,108,864 B
  short*    fcob = (short*)(ws + 67108864);                        //    557,056 B
  short*    hbuf = (short*)(ws + 67108864 + 557056);               //    262,144 B
  unsigned* cnt  = (unsigned*)(ws + 67108864 + 557056 + 262144);   //      2,048 B

  prep_kernel<<<272, 256, 0, stream>>>(fco_w, fcob, hbuf, cnt);
  lstm_kernel<<<256, 256, 0, stream>>>(x,
                                       wfx_w, wix_w, wox_w, wcx_w,
                                       wfx_b, wix_b, wox_b, wcx_b,
                                       wfh_w, wih_w, woh_w, wch_w,
                                       hs, hbuf, cnt);
  outproj_kernel<<<512, 256, 0, stream>>>(hs, fcob, fco_b, out);
}

// Round 2
// 2173.020 us; speedup vs baseline: 6.6841x; 6.6841x over previous
//
#include <hip/hip_runtime.h>

#define T_STEPS 512
#define BATCH 64
#define FDIM 256
#define HDIM 1024
#define CDIM 257

typedef __attribute__((ext_vector_type(8))) short short8;
typedef __attribute__((ext_vector_type(4))) short short4_t;
typedef __attribute__((ext_vector_type(4))) float float4_t;
typedef __attribute__((ext_vector_type(2))) int int2_t;

__device__ __forceinline__ short f2bf(float f) {
  unsigned u = __builtin_bit_cast(unsigned, f);
  unsigned r = (u + 0x7fffu + ((u >> 16) & 1u)) >> 16;   // RNE
  return (short)(r & 0xffffu);
}

__device__ __forceinline__ float sigmoid_f(float x) {
  return 1.0f / (1.0f + __expf(-x));
}
__device__ __forceinline__ float tanh_f(float x) {
  float s = __expf(-2.0f * fabsf(x));
  float t = (1.0f - s) / (1.0f + s);
  return (x < 0.0f) ? -t : t;
}

// 8 x 16B coherent (LIC-bypass) loads from base + ktl*64B, one waitcnt.
__device__ __forceinline__ void load_h_frags(const short* base, short8 (&bh)[8]) {
  float4_t r0, r1, r2, r3, r4, r5, r6, r7;
  asm volatile(
    "global_load_dwordx4 %0, %8, off sc0 sc1\n\t"
    "global_load_dwordx4 %1, %8, off offset:64 sc0 sc1\n\t"
    "global_load_dwordx4 %2, %8, off offset:128 sc0 sc1\n\t"
    "global_load_dwordx4 %3, %8, off offset:192 sc0 sc1\n\t"
    "global_load_dwordx4 %4, %8, off offset:256 sc0 sc1\n\t"
    "global_load_dwordx4 %5, %8, off offset:320 sc0 sc1\n\t"
    "global_load_dwordx4 %6, %8, off offset:384 sc0 sc1\n\t"
    "global_load_dwordx4 %7, %8, off offset:448 sc0 sc1\n\t"
    "s_waitcnt vmcnt(0)"
    : "=&v"(r0), "=&v"(r1), "=&v"(r2), "=&v"(r3),
      "=&v"(r4), "=&v"(r5), "=&v"(r6), "=&v"(r7)
    : "v"(base)
    : "memory");
  bh[0] = __builtin_bit_cast(short8, r0);
  bh[1] = __builtin_bit_cast(short8, r1);
  bh[2] = __builtin_bit_cast(short8, r2);
  bh[3] = __builtin_bit_cast(short8, r3);
  bh[4] = __builtin_bit_cast(short8, r4);
  bh[5] = __builtin_bit_cast(short8, r5);
  bh[6] = __builtin_bit_cast(short8, r6);
  bh[7] = __builtin_bit_cast(short8, r7);
}

// ---------------------------------------------------------------------------
// prep: fco fp32 -> bf16 (padded to 272 rows), zero h double-buffer + flags
// grid: 272 x 256
// ---------------------------------------------------------------------------
__global__ void prep_kernel(const float* __restrict__ fco_w,
                            short* __restrict__ fcob,
                            short* __restrict__ hbuf,
                            unsigned* __restrict__ flg)
{
  const int tid = blockIdx.x * 256 + threadIdx.x;
  {
    const int idx = tid * 4;
    const int c = idx >> 10, k = idx & 1023;
    short4_t o;
    if (c < CDIM) {
      const float4_t f = *(const float4_t*)(fco_w + c * HDIM + k);
      o[0] = f2bf(f[0]); o[1] = f2bf(f[1]); o[2] = f2bf(f[2]); o[3] = f2bf(f[3]);
    } else {
      o[0] = 0; o[1] = 0; o[2] = 0; o[3] = 0;
    }
    *(short4_t*)(fcob + idx) = o;
  }
  if (tid < 16384) {   // 2*64*1024 shorts / 8
    short8 z = (short8){0,0,0,0,0,0,0,0};
    *(short8*)(hbuf + tid * 8) = z;
  }
  if (tid < 4096) flg[tid] = 0;   // 256 flags x 16-dword pad
}

// ---------------------------------------------------------------------------
// persistent LSTM kernel: 256 WGs = 64 col-groups x 4 batch-quarters,
// 256 threads (4 waves). Wave w owns K-chunk w (256 of 1024) for all 4 gates.
// Weights live in registers as MFMA A-frags. One __syncthreads per step.
// Cross-WG sync: per-producer monotone flag (own 64B line), stored sc0sc1
// after h drains to LIC; consumers poll lane-parallel, read h with sc0sc1
// bypass loads. No fences, no atomic RMW.
// ---------------------------------------------------------------------------
__global__ __launch_bounds__(256, 1) void lstm_kernel(
    const float* __restrict__ x,
    const float* __restrict__ wfx, const float* __restrict__ wix,
    const float* __restrict__ wox, const float* __restrict__ wcx,
    const float* __restrict__ bfx, const float* __restrict__ bix,
    const float* __restrict__ box, const float* __restrict__ bcx,
    const float* __restrict__ wfh, const float* __restrict__ wih,
    const float* __restrict__ woh, const float* __restrict__ wch,
    short* __restrict__ hs, short* __restrict__ hbuf,
    unsigned* __restrict__ flg)
{
  const int tid  = threadIdx.x;
  const int lane = tid & 63;
  const int w    = tid >> 6;      // wave id == K-chunk id
  const int quad = lane >> 4;
  const int lm   = lane & 15;
  const int cg   = blockIdx.x & 63;   // column group (16 h-cols)
  const int bq   = blockIdx.x >> 6;   // batch quarter (16 rows)

  // zbuf[parity][slot = w*4+g][b(16) stride 20][i-quad 4]  (fp32, b128-aligned)
  __shared__ float zbuf[2][16 * 320];

  const float* Wh[4] = {wfh, wih, woh, wch};
  const float* Wx[4] = {wfx, wix, wox, wcx};
  const float* Bx[4] = {bfx, bix, box, bcx};

  // ---- preload weight A-fragments (bf16), K-split by wave ----
  // A[m = lane&15 -> gate-col][k = quad*8 + j]
  short8 wr[4][8];   // recurrent: gate g, local k-tile (global kt = w*8+ktl)
  short8 wxf[4][2];  // input proj: gate g, local k-tile (global kt2 = w*2+ktl)
#pragma unroll
  for (int g = 0; g < 4; ++g) {
    const float* rw = Wh[g] + (cg * 16 + lm) * HDIM;
#pragma unroll
    for (int ktl = 0; ktl < 8; ++ktl) {
      const float* pk = rw + (w * 8 + ktl) * 32 + quad * 8;
      short8 a;
#pragma unroll
      for (int j = 0; j < 8; ++j) a[j] = f2bf(pk[j]);
      wr[g][ktl] = a;
    }
    const float* rx = Wx[g] + (cg * 16 + lm) * FDIM;
#pragma unroll
    for (int ktl = 0; ktl < 2; ++ktl) {
      const float* pk = rx + (w * 2 + ktl) * 32 + quad * 8;
      short8 a;
#pragma unroll
      for (int j = 0; j < 8; ++j) a[j] = f2bf(pk[j]);
      wxf[g][ktl] = a;
    }
  }

  // wave0 epilogue state: bias per (g, i4*4+r) and cell state (4 cells/lane)
  float4_t biasv[4];
  float cst[4] = {0.f, 0.f, 0.f, 0.f};
  {
    const int i4 = lane >> 4;
#pragma unroll
    for (int g = 0; g < 4; ++g) {
#pragma unroll
      for (int r = 0; r < 4; ++r)
        biasv[g][r] = Bx[g][cg * 16 + i4 * 4 + r];
    }
  }

  // flag this wave polls: producers of K-chunk w at this bq (16 of them),
  // one per lane 0..15 (lanes 16+ duplicate lane lm).
  unsigned* myf   = flg + ((bq * 4 + w) * 16 + lm) * 16;
  // flag this WG produces (own 64B line)
  unsigned* prodf = flg + ((bq * 4 + (cg >> 4)) * 16 + (cg & 15)) * 16;

  for (int t = 0; t < T_STEPS; ++t) {
    const int p = t & 1;

    // ---- x projection: fully off the critical path (no h dependency) ----
    float4_t xf[2][2];
    {
      const float* xb = x + ((t * BATCH) + bq * 16 + lm) * FDIM;
#pragma unroll
      for (int i = 0; i < 2; ++i) {
        const float* pk = xb + (w * 2 + i) * 32 + quad * 8;
        xf[i][0] = *(const float4_t*)(pk);
        xf[i][1] = *(const float4_t*)(pk + 4);
      }
    }
    short8 bx[2];
#pragma unroll
    for (int i = 0; i < 2; ++i) {
      short8 a;
      a[0] = f2bf(xf[i][0][0]); a[1] = f2bf(xf[i][0][1]);
      a[2] = f2bf(xf[i][0][2]); a[3] = f2bf(xf[i][0][3]);
      a[4] = f2bf(xf[i][1][0]); a[5] = f2bf(xf[i][1][1]);
      a[6] = f2bf(xf[i][1][2]); a[7] = f2bf(xf[i][1][3]);
      bx[i] = a;
    }
    float4_t acc[4];
#pragma unroll
    for (int g = 0; g < 4; ++g) acc[g] = (float4_t){0.f, 0.f, 0.f, 0.f};
#pragma unroll
    for (int i = 0; i < 2; ++i) {
#pragma unroll
      for (int g = 0; g < 4; ++g)
        acc[g] = __builtin_amdgcn_mfma_f32_16x16x32_bf16(wxf[g][i], bx[i], acc[g], 0, 0, 0);
    }

    // ---- wait for the 16 producers of our K-chunk to publish h(t-1) ----
    {
      const unsigned want = (unsigned)t;
      unsigned v;
      do {
        v = __hip_atomic_load(myf, __ATOMIC_RELAXED, __HIP_MEMORY_SCOPE_SYSTEM);
      } while (__all((int)(v >= want)) == 0);
    }

    // ---- h(t-1) B-frags, coherent bypass loads straight from LIC ----
    short8 bh[8];
    load_h_frags(hbuf + (p ^ 1) * (BATCH * HDIM) + (bq * 16 + lm) * HDIM
                      + w * 256 + quad * 8, bh);

#pragma unroll
    for (int ktl = 0; ktl < 8; ++ktl) {
#pragma unroll
      for (int g = 0; g < 4; ++g)
        acc[g] = __builtin_amdgcn_mfma_f32_16x16x32_bf16(wr[g][ktl], bh[ktl], acc[g], 0, 0, 0);
    }

    // partial z (K-chunk) -> LDS. D rows = quad*4+r (i), cols = lm (b).
#pragma unroll
    for (int g = 0; g < 4; ++g)
      *(float4_t*)(&zbuf[p][(w * 4 + g) * 320 + lm * 20 + quad * 4]) = acc[g];

    __syncthreads();

    if (w == 0) {
      const int b = lane & 15, i4 = lane >> 4;   // cell (i = i4*4+r, b)
      const float* zb = &zbuf[p][b * 20 + i4 * 4];
      float4_t zs[4];
#pragma unroll
      for (int g = 0; g < 4; ++g) {
        float4_t v0 = *(const float4_t*)(zb + (0  + g) * 320);
        float4_t v1 = *(const float4_t*)(zb + (4  + g) * 320);
        float4_t v2 = *(const float4_t*)(zb + (8  + g) * 320);
        float4_t v3 = *(const float4_t*)(zb + (12 + g) * 320);
        zs[g] = (v0 + v1) + (v2 + v3) + biasv[g];
      }
      short4_t hv;
#pragma unroll
      for (int r = 0; r < 4; ++r) {
        float ff = sigmoid_f(zs[0][r]);
        float ii = sigmoid_f(zs[1][r]);
        float oo = sigmoid_f(zs[2][r]);
        float aa = tanh_f(zs[3][r]);
        float cn = ii * aa + ff * cst[r];
        cst[r] = cn;
        hv[r] = f2bf(oo * tanh_f(cn));
      }
      const int bg  = bq * 16 + b;
      const int col = cg * 16 + i4 * 4;
      // broadcast h: write-through to LIC (coherent point), then history
      {
        short* hp = hbuf + p * (BATCH * HDIM) + bg * HDIM + col;
        int2_t hv2 = __builtin_bit_cast(int2_t, hv);
        asm volatile("global_store_dwordx2 %0, %1, off sc0 sc1"
                     :: "v"(hp), "v"(hv2) : "memory");
      }
      *(short4_t*)(hs + ((t * BATCH) + bg) * HDIM + col) = hv;
      // drain all stores to visibility, then publish flag (own line, no RMW)
      asm volatile("s_waitcnt vmcnt(0)" ::: "memory");
      if (lane == 0)
        __hip_atomic_store(prodf, (unsigned)(t + 1), __ATOMIC_RELAXED,
                           __HIP_MEMORY_SCOPE_SYSTEM);
    }
  }
}

// ---------------------------------------------------------------------------
// output projection: out[m][c] = sum_k hs[m][k]*fco[c][k] + bias[c]
// M=32768 (t*64+b), N=257 (padded 272), K=1024. A-frags in regs, B from global.
// grid: 512 x 256 (each WG: 64 rows; wave w -> m-tile w)
// ---------------------------------------------------------------------------
__global__ __launch_bounds__(256, 2) void outproj_kernel(
    const short* __restrict__ hs,
    const short* __restrict__ fcob,
    const float* __restrict__ fco_bias,
    float* __restrict__ out)
{
  const int tid = threadIdx.x, lane = tid & 63, w = tid >> 6;
  const int quad = lane >> 4, lm = lane & 15;
  const int blk = blockIdx.x;

  short8 afr[32];
  const short* ar = hs + (blk * 64 + w * 16 + lm) * HDIM;
#pragma unroll
  for (int kt = 0; kt < 32; ++kt)
    afr[kt] = *(const short8*)(ar + kt * 32 + quad * 8);

  for (int nt = 0; nt < 17; ++nt) {
    float4_t a0 = (float4_t){0.f,0.f,0.f,0.f}, a1 = (float4_t){0.f,0.f,0.f,0.f};
    const short* br = fcob + (nt * 16 + lm) * HDIM + quad * 8;
#pragma unroll
    for (int kt = 0; kt < 32; kt += 2) {
      short8 b0 = *(const short8*)(br + kt * 32);
      a0 = __builtin_amdgcn_mfma_f32_16x16x32_bf16(afr[kt], b0, a0, 0, 0, 0);
      short8 b1 = *(const short8*)(br + (kt + 1) * 32);
      a1 = __builtin_amdgcn_mfma_f32_16x16x32_bf16(afr[kt + 1], b1, a1, 0, 0, 0);
    }
    const int c = nt * 16 + lm;
    if (c < CDIM) {
      const float bias = fco_bias[c];
      const int mb = blk * 64 + w * 16 + quad * 4;
#pragma unroll
      for (int r = 0; r < 4; ++r)
        out[(mb + r) * CDIM + c] = a0[r] + a1[r] + bias;
    }
  }
}

// ---------------------------------------------------------------------------
extern "C" void kernel_launch(void* const* d_in, const int* in_sizes, int n_in,
                              void* d_out, int out_size, void* d_ws, size_t ws_size,
                              hipStream_t stream) {
  (void)in_sizes; (void)n_in; (void)out_size; (void)ws_size;
  const float* x     = (const float*)d_in[0];
  const float* wfx_w = (const float*)d_in[1];
  const float* wfx_b = (const float*)d_in[2];
  const float* wix_w = (const float*)d_in[3];
  const float* wix_b = (const float*)d_in[4];
  const float* wox_w = (const float*)d_in[5];
  const float* wox_b = (const float*)d_in[6];
  const float* wcx_w = (const float*)d_in[7];
  const float* wcx_b = (const float*)d_in[8];
  const float* wfh_w = (const float*)d_in[9];
  const float* wih_w = (const float*)d_in[10];
  const float* woh_w = (const float*)d_in[11];
  const float* wch_w = (const float*)d_in[12];
  const float* fco_w = (const float*)d_in[13];
  const float* fco_b = (const float*)d_in[14];
  float* out = (float*)d_out;

  char* ws = (char*)d_ws;
  short*    hs   = (short*)(ws);                                   // 67,108,864 B
  short*    fcob = (short*)(ws + 67108864);                        //    557,056 B
  short*    hbuf = (short*)(ws + 67108864 + 557056);               //    262,144 B
  unsigned* flg  = (unsigned*)(ws + 67108864 + 557056 + 262144);   //     16,384 B

  prep_kernel<<<272, 256, 0, stream>>>(fco_w, fcob, hbuf, flg);
  lstm_kernel<<<256, 256, 0, stream>>>(x,
                                       wfx_w, wix_w, wox_w, wcx_w,
                                       wfx_b, wix_b, wox_b, wcx_b,
                                       wfh_w, wih_w, woh_w, wch_w,
                                       hs, hbuf, flg);
  outproj_kernel<<<512, 256, 0, stream>>>(hs, fcob, fco_b, out);
}